// Round 18
// baseline (35.335 us; speedup 1.0000x reference)
//
#include <hip/hip_runtime.h>
#include <hip/hip_fp16.h>
#include <math.h>

#define D_DET 512
#define N_ANG 180
#define S_IMG 512
#define NPIX  (S_IMG * S_IMG)
#define T_MAX 63                 // ramp tap truncation

__device__ __constant__ float kPI = 3.14159265358979323846f;

// ---------------------------------------------------------------------------
// Stage 1: ramp filter + int8 PAIR quantization, per-(angle,image) scale.
//   xf[d] = 0.5*r[d] + sum_{t odd,<=63} h(t)*(r[d-t]+r[d+t]), h(t)=-2/(pi t)^2
// Per row (angle a, image bc): s_row = max_d |xf[d]|; biased uint8
// q[d] = rint(xf[d]*127/s_row)+128. u16 word (a*512+d)*2+bc = (q[d+1]<<8)|q[d]
// -> stage-2 dword (a,d) = (q0[d],q0[d+1],q1[d],q1[d+1]): ONE 4B gather
// serves both images' lerp. scl[a*2+bc] = s_row/127. f[512]=0.
// Pair-endpoint storage (not f,Delta): scale bounded by max|f| (2x tighter
// than max|Delta| for high-passed data -- R17's accuracy failure).
// Grid: 90 blocks = (bc, 4 angles) x 512 threads.
// ---------------------------------------------------------------------------
__global__ __launch_bounds__(512) void ramp_filter_kernel(
    const float* __restrict__ x, unsigned short* __restrict__ xfb,
    float* __restrict__ scl) {
    __shared__ float rp[4][640];
    __shared__ float xf[4][D_DET + 1];
    __shared__ float wredl[8][4];
    __shared__ float srow[4];            // 127/s per row

    const int blk = blockIdx.x;
    const int bc  = blk / 45;            // 0..1
    const int a0  = (blk % 45) * 4;
    const int d   = threadIdx.x;

    float4 q = *(const float4*)(x + (bc * D_DET + d) * N_ANG + a0);
    rp[0][64 + d] = q.x;
    rp[1][64 + d] = q.y;
    rp[2][64 + d] = q.z;
    rp[3][64 + d] = q.w;
    if (d < 64) {
        #pragma unroll
        for (int r = 0; r < 4; ++r) { rp[r][d] = 0.0f; rp[r][576 + d] = 0.0f; }
    }
    if (d < 4) xf[d][D_DET] = 0.0f;
    __syncthreads();

    constexpr float PI_ = 3.14159265358979323846f;
    #pragma unroll
    for (int r = 0; r < 4; ++r) {
        const float* rm = &rp[r][64 + d];
        float acc = 0.5f * rm[0];
        #pragma unroll
        for (int k = 0; k < (T_MAX + 1) / 2; ++k) {
            const int   t = 2 * k + 1;
            const float h = -2.0f / (PI_ * PI_ * (float)(t * t));
            acc = fmaf(rm[-t] + rm[t], h, acc);
        }
        xf[r][d] = acc;
    }
    __syncthreads();

    // per-row absmax reduce (4 independent shfl chains)
    float g0 = fabsf(xf[0][d]);
    float g1 = fabsf(xf[1][d]);
    float g2 = fabsf(xf[2][d]);
    float g3 = fabsf(xf[3][d]);
    #pragma unroll
    for (int o = 32; o > 0; o >>= 1) {
        g0 = fmaxf(g0, __shfl_xor(g0, o, 64));
        g1 = fmaxf(g1, __shfl_xor(g1, o, 64));
        g2 = fmaxf(g2, __shfl_xor(g2, o, 64));
        g3 = fmaxf(g3, __shfl_xor(g3, o, 64));
    }
    if ((d & 63) == 0) {
        const int wv = d >> 6;
        wredl[wv][0] = g0; wredl[wv][1] = g1;
        wredl[wv][2] = g2; wredl[wv][3] = g3;
    }
    __syncthreads();
    if (d < 4) {
        float s = 1e-20f;
        #pragma unroll
        for (int wv = 0; wv < 8; ++wv) s = fmaxf(s, wredl[wv][d]);
        srow[d] = 127.0f / s;
        scl[(a0 + d) * 2 + bc] = s * (1.0f / 127.0f);
    }
    __syncthreads();

    #pragma unroll
    for (int r = 0; r < 4; ++r) {
        const float qs = srow[r];
        int q0 = (int)rintf(xf[r][d] * qs) + 128;       // [1,255]
        int q1 = (int)rintf(xf[r][d + 1] * qs) + 128;
        xfb[((a0 + r) * D_DET + d) * 2 + bc] = (unsigned short)((q1 << 8) | q0);
    }
}

// ---------------------------------------------------------------------------
// Stage 2: backprojection, 4B/lane gathers (int8 pairs), in-block angle
// split x2. Block = 512 thr: tid&255 -> pixel of 16x16 tile (8x8 wave
// patches), tid>>8 -> angle half. 1024 blocks = 32 waves/CU.
// Inner loop (~17 VALU): fma,fma,max,cvt_i32,fract, 4x cvt_f32_ubyte,
// 2x (sub, fma, fma), addr, ONE 4B gather, uniform b128 trig read.
// Bias trick: acc accumulates s_a*lerp_a (lerp in biased-uint8 space);
// the pixel-independent 128*sum(s_a) is subtracted once post-loop.
// ---------------------------------------------------------------------------
__global__ __launch_bounds__(512) void backproj_kernel(
    const unsigned* __restrict__ xfb, const float* __restrict__ scl,
    float* __restrict__ out) {
    __shared__ float4 trig4[N_ANG];      // (c*255.5, s*255.5, s0_a, s1_a)
    __shared__ float2 red[256];
    __shared__ float  sumS[2][2];        // 128 * sum of s over half, per img
    const int tid = threadIdx.x;
    if (tid < N_ANG) {
        float th = (float)tid * (kPI / 180.0f);
        float s, c;
        sincosf(th, &s, &c);
        trig4[tid] = make_float4(c * 255.5f, s * 255.5f,
                                 scl[tid * 2], scl[tid * 2 + 1]);
    }
    __syncthreads();
    if (tid < 4) {
        const int h = tid >> 1, im = tid & 1;
        float s = 0.0f;
        for (int a = h * 90; a < h * 90 + 90; ++a)
            s += im ? trig4[a].w : trig4[a].z;
        sumS[h][im] = s * 128.0f;
    }
    __syncthreads();

    const int bi   = blockIdx.x >> 5;    // 32 i-tiles of 16
    const int bj   = blockIdx.x & 31;    // 32 j-tiles of 16
    const int half = tid >> 8;           // angle half
    const int sub  = (tid >> 6) & 3;     // wave within half
    const int lane = tid & 63;
    const int px   = tid & 255;
    const int i = (bi << 4) + ((sub >> 1) << 3) + (lane >> 3);
    const int j = (bj << 4) + ((sub & 1) << 3) + (lane & 7);

    const float xP = (float)j * (2.0f / 511.0f) - 1.0f;
    const float yP = (float)i * (2.0f / 511.0f) - 1.0f;
    const float m  = xP * xP + yP * yP;
    const bool inc = (m <= 1.0f);
    const float xS = inc ? xP : 0.0f;    // sanitize: out-circle -> pc=255.5
    const float yS = inc ? yP : 0.0f;

    float a0 = 0.0f, a1 = 0.0f;
    if (__any(inc)) {
        const int abeg = half * 90;
        #pragma unroll 6
        for (int a = abeg; a < abeg + 90; ++a) {
            float4 t  = trig4[a];                              // uniform b128
            float pc  = fmaf(xS, t.x, fmaf(yS, -t.y, 255.5f));
            pc        = fmaxf(pc, 0.0f);
            int   fi  = (int)pc;                               // trunc==floor
            float w   = __builtin_amdgcn_fractf(pc);
            unsigned g = xfb[(a << 9) + fi];                   // 4B gather
            float u0  = (float)(g & 0xffu);          // cvt_f32_ubyte0
            float u1  = (float)((g >> 8) & 0xffu);   // cvt_f32_ubyte1
            float v0  = (float)((g >> 16) & 0xffu);  // cvt_f32_ubyte2
            float v1  = (float)(g >> 24);            // cvt_f32_ubyte3
            float l0  = fmaf(w, u1 - u0, u0);
            float l1  = fmaf(w, v1 - v0, v0);
            a0 = fmaf(t.z, l0, a0);
            a1 = fmaf(t.w, l1, a1);
        }
        a0 -= sumS[half][0];             // remove 128-bias contribution
        a1 -= sumS[half][1];
    }

    if (half == 1) red[px] = make_float2(a0, a1);
    __syncthreads();
    if (half == 0) {
        const float2 r = red[px];
        const float msk = inc ? (kPI / (2.0f * (float)N_ANG)) : 0.0f;
        const int p = i * S_IMG + j;
        out[p]        = (a0 + r.x) * msk;
        out[NPIX + p] = (a1 + r.y) * msk;
    }
}

// ---------------------------------------------------------------------------
extern "C" void kernel_launch(void* const* d_in, const int* in_sizes, int n_in,
                              void* d_out, int out_size, void* d_ws, size_t ws_size,
                              hipStream_t stream) {
    const float*    x   = (const float*)d_in[0];
    float*          out = (float*)d_out;
    unsigned short* xfb = (unsigned short*)d_ws;              // 368,640 B
    float*          scl = (float*)((char*)d_ws + 368640);     // 1,440 B

    ramp_filter_kernel<<<90, 512, 0, stream>>>(x, xfb, scl);
    backproj_kernel<<<1024, 512, 0, stream>>>((const unsigned*)xfb, scl, out);
}

// Round 19
// 27.183 us; speedup vs baseline: 1.2999x; 1.2999x over previous
//
#include <hip/hip_runtime.h>
#include <hip/hip_fp16.h>
#include <math.h>

#define D_DET 512
#define N_ANG 180
#define S_IMG 512
#define NPIX  (S_IMG * S_IMG)
#define T_MAX 63                 // ramp tap truncation
#define WIN   32                 // LDS detector window cells (16x16 tile: span<=23)

typedef _Float16 half2v __attribute__((ext_vector_type(2)));

__device__ __constant__ float kPI = 3.14159265358979323846f;

__device__ __forceinline__ half2v pack_w1(float w) {
    return __builtin_bit_cast(half2v, __builtin_amdgcn_cvt_pkrtz(1.0f, w));
}

// ---------------------------------------------------------------------------
// Stage 1: ramp filter (R16 verbatim): truncated symmetric convolution,
// (f, DELTA) fp16 packing. word (a*512+d)*2+bc = fp16x2 (xf[d], xf[d+1]-xf[d]).
// Grid: 90 blocks = (bc, 4 angles) x 512 threads; float4 input loads.
// ---------------------------------------------------------------------------
__global__ __launch_bounds__(512) void ramp_filter_kernel(
    const float* __restrict__ x, unsigned* __restrict__ xfh) {
    __shared__ float rp[4][640];
    __shared__ float xf[4][D_DET + 1];

    const int blk = blockIdx.x;
    const int bc  = blk / 45;            // 0..1
    const int a0  = (blk % 45) * 4;
    const int d   = threadIdx.x;

    float4 q = *(const float4*)(x + (bc * D_DET + d) * N_ANG + a0);
    rp[0][64 + d] = q.x;
    rp[1][64 + d] = q.y;
    rp[2][64 + d] = q.z;
    rp[3][64 + d] = q.w;
    if (d < 64) {
        #pragma unroll
        for (int r = 0; r < 4; ++r) { rp[r][d] = 0.0f; rp[r][576 + d] = 0.0f; }
    }
    if (d < 4) xf[d][D_DET] = 0.0f;
    __syncthreads();

    constexpr float PI_ = 3.14159265358979323846f;
    #pragma unroll
    for (int r = 0; r < 4; ++r) {
        const float* rm = &rp[r][64 + d];
        float acc = 0.5f * rm[0];
        #pragma unroll
        for (int k = 0; k < (T_MAX + 1) / 2; ++k) {
            const int   t = 2 * k + 1;
            const float h = -2.0f / (PI_ * PI_ * (float)(t * t));
            acc = fmaf(rm[-t] + rm[t], h, acc);
        }
        xf[r][d] = acc;
    }
    __syncthreads();

    #pragma unroll
    for (int r = 0; r < 4; ++r) {
        const float f0 = xf[r][d];
        const float dl = xf[r][d + 1] - f0;
        const unsigned lo = __half_as_ushort(__float2half_rn(f0));
        const unsigned hi = __half_as_ushort(__float2half_rn(dl));
        xfh[((a0 + r) * D_DET + d) * 2 + bc] = (hi << 16) | lo;
    }
}

// ---------------------------------------------------------------------------
// Stage 2: backprojection, DUAL-PIPE angle split.
// Block = 512 thr over a 16x16 pixel tile: tid>>8 = angle half.
//   half 0: angles 0..89   -> GLOBAL 8B gathers (vector-memory pipe)
//   half 1: angles 90..179 -> LDS window reads (LDS pipe), windows staged
//           once per block (90 angles x 32 cells x 8B = 23 KB, coalesced).
// The two pipes process concurrently across waves (m114) -> the fixed
// ~16-20cyc/wave-op scatter cost is paid in parallel, not serially.
// trig4[a] = (c*255.5, s*255.5, bias(=255.5 or 255.5-dmin), dmin_f).
// Identical lerp arithmetic both halves -> absmax unchanged vs R16.
// ---------------------------------------------------------------------------
__global__ __launch_bounds__(512) void backproj_kernel(
    const uint2* __restrict__ xfh, float* __restrict__ out) {
    __shared__ float4 trig4[N_ANG];
    __shared__ uint2  win[90 * WIN];     // 23 KB window buffer (angles 90..179)
    __shared__ float2 red[256];

    const int tid = threadIdx.x;
    const int bi  = blockIdx.x >> 5;     // 32 i-tiles of 16
    const int bj  = blockIdx.x & 31;     // 32 j-tiles of 16
    const int i0  = bi << 4;
    const int j0  = bj << 4;

    // Prologue: trig + per-angle window start (angles >= 90 only).
    if (tid < N_ANG) {
        float th = (float)tid * (kPI / 180.0f);
        float s, c;
        sincosf(th, &s, &c);
        float c5 = c * 255.5f, s5 = s * 255.5f;
        float bias = 255.5f, dmf = 0.0f;
        if (tid >= 90) {
            float x0 = (float)j0 * (2.0f / 511.0f) - 1.0f;
            float x1 = (float)(j0 + 15) * (2.0f / 511.0f) - 1.0f;
            float y0 = (float)i0 * (2.0f / 511.0f) - 1.0f;
            float y1 = (float)(i0 + 15) * (2.0f / 511.0f) - 1.0f;
            float pmin = 255.5f + fminf(c5 * x0, c5 * x1)
                                + fminf(-s5 * y0, -s5 * y1);
            int dmin = (int)floorf(pmin) - 1;
            dmin = dmin < 0 ? 0 : (dmin > (D_DET - WIN) ? (D_DET - WIN) : dmin);
            dmin &= ~1;                  // 16B-aligned staging source
            bias = 255.5f - (float)dmin;
            dmf  = (float)dmin;
        }
        trig4[tid] = make_float4(c5, s5, bias, dmf);
    }
    __syncthreads();

    // Stage windows: 90 angles x 16 uint4 = 1440 uint4, coalesced from L2.
    {
        const uint4* __restrict__ src4 = (const uint4*)xfh;
        uint4* win4 = (uint4*)win;
        #pragma unroll
        for (int f = tid; f < 90 * (WIN / 2); f += 512) {
            int a    = f >> 4;           // WIN/2 = 16 uint4 per angle
            int e    = f & 15;
            int ag   = 90 + a;
            int dmin = (int)trig4[ag].w;
            win4[f]  = src4[((ag << 9) + dmin) >> 1];
            win4[f]  = src4[(((ag << 9) + dmin) >> 1) + e];
        }
    }
    __syncthreads();

    const int half = tid >> 8;
    const int sub  = (tid >> 6) & 3;
    const int lane = tid & 63;
    const int px   = tid & 255;
    const int i = i0 + ((sub >> 1) << 3) + (lane >> 3);
    const int j = j0 + ((sub & 1) << 3) + (lane & 7);

    const float xP = (float)j * (2.0f / 511.0f) - 1.0f;
    const float yP = (float)i * (2.0f / 511.0f) - 1.0f;
    const float m  = xP * xP + yP * yP;
    const bool inc = (m <= 1.0f);
    const float xS = inc ? xP : 0.0f;    // sanitize: out-circle -> pc=255.5
    const float yS = inc ? yP : 0.0f;

    float a0 = 0.0f, a1 = 0.0f;
    if (__any(inc)) {
        if (half == 0) {
            // vector-memory pipe: global 8B gathers
            #pragma unroll 6
            for (int a = 0; a < 90; ++a) {
                float4 t  = trig4[a];
                float pc  = fmaf(xS, t.x, fmaf(yS, -t.y, 255.5f));
                pc        = fmaxf(pc, 0.0f);
                int   fi  = (int)pc;
                float w   = __builtin_amdgcn_fractf(pc);
                half2v hw = pack_w1(w);
                uint2  g  = xfh[(a << 9) + fi];
                a0 = __builtin_amdgcn_fdot2(hw, __builtin_bit_cast(half2v, g.x), a0, false);
                a1 = __builtin_amdgcn_fdot2(hw, __builtin_bit_cast(half2v, g.y), a1, false);
            }
        } else {
            // LDS pipe: window reads; bias folds the window start
            #pragma unroll 6
            for (int a = 90; a < N_ANG; ++a) {
                float4 t  = trig4[a];
                float pc  = fmaf(xS, t.x, fmaf(yS, -t.y, t.z));  // pc - dmin
                pc        = fminf(fmaxf(pc, 0.0f), (float)(WIN - 1));
                int   fi  = (int)pc;
                float w   = __builtin_amdgcn_fractf(pc);
                half2v hw = pack_w1(w);
                uint2  g  = win[((a - 90) << 5) + fi];
                a0 = __builtin_amdgcn_fdot2(hw, __builtin_bit_cast(half2v, g.x), a0, false);
                a1 = __builtin_amdgcn_fdot2(hw, __builtin_bit_cast(half2v, g.y), a1, false);
            }
        }
    }

    if (half == 1) red[px] = make_float2(a0, a1);
    __syncthreads();
    if (half == 0) {
        const float2 r = red[px];
        const float msk = inc ? (kPI / (2.0f * (float)N_ANG)) : 0.0f;
        const int p = i * S_IMG + j;
        out[p]        = (a0 + r.x) * msk;
        out[NPIX + p] = (a1 + r.y) * msk;
    }
}

// ---------------------------------------------------------------------------
extern "C" void kernel_launch(void* const* d_in, const int* in_sizes, int n_in,
                              void* d_out, int out_size, void* d_ws, size_t ws_size,
                              hipStream_t stream) {
    const float* x   = (const float*)d_in[0];
    float*       out = (float*)d_out;
    unsigned*    xfh = (unsigned*)d_ws;  // 737,280 B

    ramp_filter_kernel<<<90, 512, 0, stream>>>(x, xfh);
    backproj_kernel<<<1024, 512, 0, stream>>>((const uint2*)xfh, out);
}